// Round 7
// baseline (4586.274 us; speedup 1.0000x reference)
//
#include <hip/hip_runtime.h>

// 2D acoustic FD, 4 shots x 1000 steps. Temporal blocking K=8, 9 x-chunks/shot,
// full z in LDS (transposed [x-row][z-col]). R7: 8-wide z per thread (lf/rt
// amortized), u_prev held in REGISTERS (no pv LDS read; halo prevs refreshed
// from ingested u(t+7) once per round), ZW=164 for bank-balanced b128 reads.
// Protocol identical to R6 (agent-scope publish, flags, batched sc0sc1 ingest).

#define NZ_ 150
#define NX_ 300
#define NT_ 1000
#define NS_ 4
#define NR_ 400
#define KS_ 8
#define NCH_ 9
#define NBND_ 8
#define HW_ 32               // halo width = 4*KS
#define ZW_ 164              // bank-balanced: 164 % 8 == 4 (rows spread all 32 banks)
#define LROWS_ 98            // 32 + 34 + 32
#define BUF_ (LROWS_*ZW_)
#define THR_ 320
#define NRND_ 125
#define HELE_ 4800           // u64 per (s,bnd,dir,par): 2 fields*32 rows*75 zpairs
#define NBATCH 30            // 4800 / 160

typedef float f4 __attribute__((ext_vector_type(4)));
typedef unsigned long long u64;

__device__ __forceinline__ void astore64(u64* p, u64 v) {
    __hip_atomic_store(p, v, __ATOMIC_RELAXED, __HIP_MEMORY_SCOPE_AGENT);
}
__device__ __forceinline__ int aload32(const int* p) {
    return __hip_atomic_load(p, __ATOMIC_RELAXED, __HIP_MEMORY_SCOPE_AGENT);
}
__device__ __forceinline__ void astore32(int* p, int v) {
    __hip_atomic_store(p, v, __ATOMIC_RELAXED, __HIP_MEMORY_SCOPE_AGENT);
}
__device__ __forceinline__ void ld2_issue(u64& d, const u64* p) {
    asm volatile("global_load_dwordx2 %0, %1, off sc0 sc1" : "=v"(d) : "v"(p));
}

__global__ __launch_bounds__(THR_) void wave_rp(
    const float* __restrict__ v_map, const float* __restrict__ s_amp,
    const int* __restrict__ s_loc, const int* __restrict__ r_loc,
    float* __restrict__ out, int* __restrict__ flags, u64* __restrict__ halo)
{
    extern __shared__ float smem[];
    const int bi = blockIdx.x;
    const int s = bi & 3;
    const int h = bi >> 2;                       // 0..8
    const int tid = threadIdx.x;

    const int w   = 33 + (h < 3 ? 1 : 0);
    const int x0  = 33*h + (h < 3 ? h : 3);
    const int rhi = HW_ + w;

    for (int i = tid; i < 2*BUF_; i += THR_) smem[i] = 0.0f;

    const int zg = tid % 19;                     // 8-wide z group: cols c0..c0+7
    const int xp = tid / 19;                     // x-slice of 7 rows
    const bool comp = (tid < 266);               // 19*14
    const int c0 = 4 + 8*zg;
    const int rbase = 7*xp;

    f4 v2A[7], v2B[7];
#pragma unroll
    for (int i = 0; i < 7; ++i) {
        f4 a = {0.f,0.f,0.f,0.f}, b = {0.f,0.f,0.f,0.f};
        const int row = rbase + i;
        const int x = x0 - HW_ + row;
        if (comp && x >= 0 && x < NX_) {
#pragma unroll
            for (int j = 0; j < 8; ++j) {
                const int z = 8*zg + j;
                float val = 0.0f;
                if (z < NZ_) { const float v = v_map[z*NX_ + x]*0.001f; val = v*v*0.01f; }
                if (j < 4) a[j] = val; else b[j-4] = val;
            }
        }
        v2A[i] = a; v2B[i] = b;
    }

    const int sz = s_loc[2*s], sx = s_loc[2*s+1];
    float sS = v_map[sz*NX_+sx]*0.001f; sS *= sS;          // (v*DT)^2
    const int srow = sx - x0 + HW_;
    const bool hasS = comp && (zg == (sz >> 3)) && (srow >= rbase) && (srow < rbase+7);
    const int sel = sz & 7;

    int nrec = 0; int rI[2], rRow[2], rCol[2];
#pragma unroll
    for (int q = 0; q < 2; ++q) {
        const int rr = tid + q*THR_;
        if (rr < NR_) {
            const int rz = r_loc[2*rr], rx = r_loc[2*rr+1];
            if (rx >= x0 && rx < x0+w) { rI[nrec]=rr; rRow[nrec]=HW_+rx-x0; rCol[nrec]=4+rz; ++nrec; }
        }
    }

    f4 pA[7], pB[7];                              // u_prev in registers
#pragma unroll
    for (int i = 0; i < 7; ++i) { pA[i] = f4{0.f,0.f,0.f,0.f}; pB[i] = f4{0.f,0.f,0.f,0.f}; }

    __syncthreads();

    for (int r = 0; r < NRND_; ++r) {
        for (int k = 1; k <= KS_; ++k) {
            const int tau = KS_*r + k;
            const int ext = 4*(KS_-k);                     // 28..0
            const int L = (h==0)        ? HW_ : HW_-ext;
            const int R = (h==NCH_-1)   ? rhi : rhi+ext;
            const float* cur = smem + ((tau+1)&1)*BUF_;
            float*       nxt = smem + (tau&1)*BUF_;
            const float amp = s_amp[s*NT_ + tau - 1];      // uniform, cached

            if (comp && rbase < R && rbase+7 > L) {
                f4 WA[9], WB[9];
#pragma unroll
                for (int q = 0; q < 8; ++q) {
                    int rr = rbase-4+q; rr = rr < 0 ? 0 : rr;
                    WA[q] = *(const f4*)&cur[rr*ZW_ + c0];
                    WB[q] = *(const f4*)&cur[rr*ZW_ + c0+4];
                }
#pragma unroll
                for (int i = 0; i < 7; ++i) {
                    const int row = rbase+i;
                    const int wr = (row+4 < LROWS_) ? row+4 : LROWS_-1;
                    WA[8] = *(const f4*)&cur[wr*ZW_ + c0];
                    WB[8] = *(const f4*)&cur[wr*ZW_ + c0+4];
                    if (row >= L && row < R) {
                        const f4 lf = *(const f4*)&cur[row*ZW_ + c0-4];
                        const f4 rt = *(const f4*)&cur[row*ZW_ + c0+8];
                        float xw[16];
#pragma unroll
                        for (int j = 0; j < 4; ++j) {
                            xw[j] = lf[j]; xw[4+j] = WA[4][j]; xw[8+j] = WB[4][j]; xw[12+j] = rt[j];
                        }
                        f4 rA, rB;
#pragma unroll
                        for (int j = 0; j < 4; ++j) {
                            const float ct = xw[4+j];
                            float lap = 2.0f*(-205.0f/72.0f)*ct;
                            lap += (8.0f/5.0f)   *((xw[j+3]+xw[j+5])  + (WA[3][j]+WA[5][j]));
                            lap += (-1.0f/5.0f)  *((xw[j+2]+xw[j+6])  + (WA[2][j]+WA[6][j]));
                            lap += (8.0f/315.0f) *((xw[j+1]+xw[j+7])  + (WA[1][j]+WA[7][j]));
                            lap += (-1.0f/560.0f)*((xw[j+0]+xw[j+8])  + (WA[0][j]+WA[8][j]));
                            rA[j] = 2.0f*ct - pA[i][j] + v2A[i][j]*lap;
                        }
#pragma unroll
                        for (int j = 0; j < 4; ++j) {
                            const float ct = xw[8+j];
                            float lap = 2.0f*(-205.0f/72.0f)*ct;
                            lap += (8.0f/5.0f)   *((xw[j+7]+xw[j+9])  + (WB[3][j]+WB[5][j]));
                            lap += (-1.0f/5.0f)  *((xw[j+6]+xw[j+10]) + (WB[2][j]+WB[6][j]));
                            lap += (8.0f/315.0f) *((xw[j+5]+xw[j+11]) + (WB[1][j]+WB[7][j]));
                            lap += (-1.0f/560.0f)*((xw[j+4]+xw[j+12]) + (WB[0][j]+WB[8][j]));
                            rB[j] = 2.0f*ct - pB[i][j] + v2B[i][j]*lap;
                        }
                        if (hasS && row == srow) {
                            const float add = sS*amp;
#pragma unroll
                            for (int j = 0; j < 4; ++j) {
                                if (sel == j)   rA[j] += add;
                                if (sel == 4+j) rB[j] += add;
                            }
                        }
                        *(f4*)&nxt[row*ZW_ + c0]   = rA;
                        *(f4*)&nxt[row*ZW_ + c0+4] = rB;
                    }
                    pA[i] = WA[4]; pB[i] = WB[4];          // prev := u(tau-1), always
#pragma unroll
                    for (int q = 0; q < 8; ++q) { WA[q] = WA[q+1]; WB[q] = WB[q+1]; }
                }
            }
            __syncthreads();
            if (nrec) {
                const float* nb = smem + (tau&1)*BUF_;
                out[((size_t)s*NT_+(tau-1))*NR_ + rI[0]] = nb[rRow[0]*ZW_ + rCol[0]];
                if (nrec > 1)
                    out[((size_t)s*NT_+(tau-1))*NR_ + rI[1]] = nb[rRow[1]*ZW_ + rCol[1]];
            }
        }

        if (r < NRND_-1) {
            const int par = r & 1;
            // ---- publish 32 interior edge cols of u(t+8)=buf0, u(t+7)=buf1 ----
            if (tid < 160) {
                if (h > 0) {
                    u64* dst = halo + (size_t)(((s*NBND_ + h-1)*2 + 1)*2 + par)*HELE_;
                    for (int e = tid; e < HELE_; e += 160) {
                        const int f = e/2400, rem = e - f*2400, row = rem/75, zp = rem - row*75;
                        astore64(dst + e, *(const u64*)&smem[f*BUF_ + (HW_+row)*ZW_ + 4 + 2*zp]);
                    }
                }
            } else {
                if (h < NCH_-1) {
                    u64* dst = halo + (size_t)(((s*NBND_ + h)*2 + 0)*2 + par)*HELE_;
                    for (int e = tid-160; e < HELE_; e += 160) {
                        const int f = e/2400, rem = e - f*2400, row = rem/75, zp = rem - row*75;
                        astore64(dst + e, *(const u64*)&smem[f*BUF_ + (w+row)*ZW_ + 4 + 2*zp]);
                    }
                }
            }
            asm volatile("s_waitcnt vmcnt(0)" ::: "memory");   // drain own publishes
            __syncthreads();
            if (tid == 0) {
                if (h > 0)      astore32(&flags[(s*NBND_ + h-1)*2 + 1], r+1);
                if (h < NCH_-1) astore32(&flags[(s*NBND_ + h)*2 + 0], r+1);
            }
            // ---- distributed poll + batched ingest (1 vmcnt wait) ----
            if (tid < 160) {
                if (h > 0) {
                    const int* fp = &flags[(s*NBND_ + h-1)*2 + 0];
                    while (aload32(fp) <= r) __builtin_amdgcn_s_sleep(1);
                    const u64* src = halo + (size_t)(((s*NBND_ + h-1)*2 + 0)*2 + par)*HELE_;
                    u64 vb[NBATCH];
#pragma unroll
                    for (int q = 0; q < NBATCH; ++q) {
                        const int e = tid + 160*q;
                        ld2_issue(vb[q], src + (e < HELE_ ? e : HELE_-1));
                    }
                    asm volatile("s_waitcnt vmcnt(0)" ::: "memory");
                    __builtin_amdgcn_sched_barrier(0);
#pragma unroll
                    for (int q = 0; q < NBATCH; ++q) {
                        const int e = tid + 160*q;
                        if (e < HELE_) {
                            const int f = e/2400, rem = e - f*2400, row = rem/75, zp = rem - row*75;
                            *(u64*)&smem[f*BUF_ + row*ZW_ + 4 + 2*zp] = vb[q];
                        }
                    }
                }
            } else {
                if (h < NCH_-1) {
                    const int* fp = &flags[(s*NBND_ + h)*2 + 1];
                    while (aload32(fp) <= r) __builtin_amdgcn_s_sleep(1);
                    const u64* src = halo + (size_t)(((s*NBND_ + h)*2 + 1)*2 + par)*HELE_;
                    u64 vb[NBATCH];
#pragma unroll
                    for (int q = 0; q < NBATCH; ++q) {
                        const int e = (tid-160) + 160*q;
                        ld2_issue(vb[q], src + (e < HELE_ ? e : HELE_-1));
                    }
                    asm volatile("s_waitcnt vmcnt(0)" ::: "memory");
                    __builtin_amdgcn_sched_barrier(0);
#pragma unroll
                    for (int q = 0; q < NBATCH; ++q) {
                        const int e = (tid-160) + 160*q;
                        if (e < HELE_) {
                            const int f = e/2400, rem = e - f*2400, row = rem/75, zp = rem - row*75;
                            *(u64*)&smem[f*BUF_ + (rhi+row)*ZW_ + 4 + 2*zp] = vb[q];
                        }
                    }
                }
            }
            __syncthreads();
            // ---- refresh register-prev for halo rows from ingested u(t+7) (buf1) ----
            if (comp) {
#pragma unroll
                for (int i = 0; i < 7; ++i) {
                    const int row = rbase + i;
                    if (row < HW_ || row >= rhi) {
                        pA[i] = *(const f4*)&smem[BUF_ + row*ZW_ + c0];
                        pB[i] = *(const f4*)&smem[BUF_ + row*ZW_ + c0+4];
                    }
                }
            }
            __syncthreads();
        }
    }
}

extern "C" void kernel_launch(void* const* d_in, const int* in_sizes, int n_in,
                              void* d_out, int out_size, void* d_ws, size_t ws_size,
                              hipStream_t stream) {
    const float* v_map = (const float*)d_in[0];
    const float* s_amp = (const float*)d_in[1];
    const int*   s_loc = (const int*)d_in[2];
    const int*   r_loc = (const int*)d_in[3];
    float* out = (float*)d_out;

    int* flags = (int*)d_ws;                        // 64 ints
    u64* halo  = (u64*)((char*)d_ws + 1024);        // 4*8*2*2*4800*8 = 4.92 MB

    hipMemsetAsync(d_ws, 0, 1024, stream);          // reset flags each call

    const int smem_bytes = 2 * BUF_ * 4;            // 128,576 B
    static bool attr_set = false;
    if (!attr_set) {                                // host-side, idempotent
        hipFuncSetAttribute((const void*)wave_rp,
                            hipFuncAttributeMaxDynamicSharedMemorySize, smem_bytes);
        attr_set = true;
    }

    wave_rp<<<dim3(NS_ * NCH_), dim3(THR_), smem_bytes, stream>>>(
        v_map, s_amp, s_loc, r_loc, out, flags, halo);
}

// Round 8
// 3080.770 us; speedup vs baseline: 1.4887x; 1.4887x over previous
//
#include <hip/hip_runtime.h>

// 2D acoustic FD, 4 shots x 1000 steps. Temporal blocking K=8:
// 9 x-chunks/shot (33-34 interior cols), full z in LDS (transposed layout),
// 32-col halos of {u(t+8),u(t+7)} exchanged every 8 steps via agent-scope
// protocol with batched sc0sc1 ingest (R6). R8: u_prev kept in REGISTERS
// (saves the pv LDS read, -17% LDS ops); halo-row prevs refreshed from the
// ingested u(t+7) once per round. Layout/protocol byte-identical to R6.

#define NZ_ 150
#define NX_ 300
#define NT_ 1000
#define NS_ 4
#define NR_ 400
#define KS_ 8
#define NCH_ 9
#define NBND_ 8
#define HW_ 32               // halo width = 4*KS
#define ZW_ 168              // LDS z-stride (4 pad + 150 + 4 pad + align)
#define LROWS_ 98            // 32 + 34 + 32 max rows per chunk
#define BUF_ (LROWS_*ZW_)
#define THR_ 512
#define NRND_ 125
#define HELE_ 4800           // u64 per (s,bnd,dir,par): 2 fields*32 rows*75 zpairs
#define NBATCH 19            // ceil(4800/256)

typedef float f4 __attribute__((ext_vector_type(4)));
typedef unsigned long long u64;

__device__ __forceinline__ void astore64(u64* p, u64 v) {
    __hip_atomic_store(p, v, __ATOMIC_RELAXED, __HIP_MEMORY_SCOPE_AGENT);
}
__device__ __forceinline__ int aload32(const int* p) {
    return __hip_atomic_load(p, __ATOMIC_RELAXED, __HIP_MEMORY_SCOPE_AGENT);
}
__device__ __forceinline__ void astore32(int* p, int v) {
    __hip_atomic_store(p, v, __ATOMIC_RELAXED, __HIP_MEMORY_SCOPE_AGENT);
}
// batched ingest: issue without waiting; sc0 sc1 = bypass L1+L2, read MALL
__device__ __forceinline__ void ld2_issue(u64& d, const u64* p) {
    asm volatile("global_load_dwordx2 %0, %1, off sc0 sc1" : "=v"(d) : "v"(p));
}

__global__ __launch_bounds__(THR_) void wave_rp2(
    const float* __restrict__ v_map, const float* __restrict__ s_amp,
    const int* __restrict__ s_loc, const int* __restrict__ r_loc,
    float* __restrict__ out, int* __restrict__ flags, u64* __restrict__ halo)
{
    extern __shared__ float smem[];
    const int bi = blockIdx.x;
    const int s = bi & 3;
    const int h = bi >> 2;                       // 0..8
    const int tid = threadIdx.x;

    const int w  = 33 + (h < 3 ? 1 : 0);
    const int x0 = 33 * h + (h < 3 ? h : 3);
    const int rhi = HW_ + w;

    for (int i = tid; i < 2 * BUF_; i += THR_) smem[i] = 0.0f;

    const int zg = tid % 38;                     // 4-wide z group (R6 layout)
    const int xp = tid / 38;                     // x-slice, 8 rows each
    const bool comp = (tid < 494);               // 38*13
    const int c0 = 4 + 4 * zg;
    const int rbase = 8 * xp;

    f4 v2r[8];
#pragma unroll
    for (int i = 0; i < 8; ++i) {
        f4 vv = {0.f, 0.f, 0.f, 0.f};
        const int row = rbase + i;
        const int x = x0 - HW_ + row;
        if (comp && x >= 0 && x < NX_) {
#pragma unroll
            for (int j = 0; j < 4; ++j) {
                const int z = min(4 * zg + j, NZ_ - 1);
                const float v = v_map[z * NX_ + x] * 0.001f;
                vv[j] = v * v * 0.01f;           // (v*DT)^2 / DX^2
            }
        }
        v2r[i] = vv;
    }

    const int sz = s_loc[2 * s], sx = s_loc[2 * s + 1];
    float sS = v_map[sz * NX_ + sx] * 0.001f; sS = sS * sS;   // (v*DT)^2
    const int srow = sx - x0 + HW_;
    const int szg = sz >> 2;
    const int scol = 4 + sz;

    bool rown = false; int rrow = 0, rcol = 0;
    if (tid < NR_) {
        const int rz = r_loc[2 * tid];
        const int rx = r_loc[2 * tid + 1];
        if (rx >= x0 && rx < x0 + w) { rown = true; rrow = HW_ + rx - x0; rcol = 4 + rz; }
    }

    f4 pv_r[8];                                   // u_prev in registers
#pragma unroll
    for (int i = 0; i < 8; ++i) pv_r[i] = f4{0.f, 0.f, 0.f, 0.f};

    __syncthreads();

    for (int r = 0; r < NRND_; ++r) {
        for (int k = 1; k <= KS_; ++k) {
            const int tau = KS_ * r + k;
            const int ext = 4 * (KS_ - k);                     // 28..0
            const int L  = (h == 0)        ? HW_ : HW_ - ext;
            const int R  = (h == NCH_ - 1) ? rhi : rhi + ext;
            const float* cur = smem + ((tau + 1) & 1) * BUF_;
            float*       nxt = smem + (tau & 1) * BUF_;

            if (comp && rbase < R && rbase + 8 > L) {
                f4 W[9];
#pragma unroll
                for (int q = 0; q < 8; ++q) {
                    int rr = rbase - 4 + q; rr = rr < 0 ? 0 : rr;
                    W[q] = *(const f4*)&cur[rr * ZW_ + c0];
                }
#pragma unroll
                for (int i = 0; i < 8; ++i) {
                    const int row = rbase + i;
                    const int wr = (row + 4 < LROWS_) ? (row + 4) : (LROWS_ - 1);
                    W[8] = *(const f4*)&cur[wr * ZW_ + c0];
                    if (row >= L && row < R) {
                        const f4 lf = *(const f4*)&cur[row * ZW_ + c0 - 4];
                        const f4 rt = *(const f4*)&cur[row * ZW_ + c0 + 4];
                        float xw[12];
#pragma unroll
                        for (int j = 0; j < 4; ++j) { xw[j] = lf[j]; xw[4 + j] = W[4][j]; xw[8 + j] = rt[j]; }
                        f4 res;
#pragma unroll
                        for (int j = 0; j < 4; ++j) {
                            const float ct = xw[4 + j];
                            float lap = 2.0f * (-205.0f / 72.0f) * ct;
                            lap += (8.0f / 5.0f)    * ((xw[j + 3] + xw[j + 5]) + (W[3][j] + W[5][j]));
                            lap += (-1.0f / 5.0f)   * ((xw[j + 2] + xw[j + 6]) + (W[2][j] + W[6][j]));
                            lap += (8.0f / 315.0f)  * ((xw[j + 1] + xw[j + 7]) + (W[1][j] + W[7][j]));
                            lap += (-1.0f / 560.0f) * ((xw[j + 0] + xw[j + 8]) + (W[0][j] + W[8][j]));
                            res[j] = 2.0f * ct - pv_r[i][j] + v2r[i][j] * lap;
                        }
                        if (zg != 37) {
                            *(f4*)&nxt[row * ZW_ + c0] = res;
                        } else {                               // z=148,149; keep pads zero
                            nxt[row * ZW_ + c0]     = res[0];
                            nxt[row * ZW_ + c0 + 1] = res[1];
                        }
                        if (row == srow && zg == szg)
                            nxt[row * ZW_ + scol] += sS * s_amp[s * NT_ + tau - 1];
                    }
                    pv_r[i] = W[4];   // prev := u(tau-1)[row]; valid whenever later used
#pragma unroll
                    for (int q = 0; q < 8; ++q) W[q] = W[q + 1];
                }
            }
            __syncthreads();
            if (rown) {
                const float* nb = smem + (tau & 1) * BUF_;
                out[((size_t)s * NT_ + (tau - 1)) * NR_ + tid] = nb[rrow * ZW_ + rcol];
            }
        }

        if (r < NRND_ - 1) {
            const int par = r & 1;
            // ---- publish 32 interior edge cols of u(t+8)=buf0, u(t+7)=buf1 ----
            if (tid < 256) {
                if (h > 0) {
                    u64* dst = halo + (size_t)(((s * NBND_ + h - 1) * 2 + 1) * 2 + par) * HELE_;
                    for (int e = tid; e < HELE_; e += 256) {
                        const int f = e / 2400, rem = e - f * 2400, row = rem / 75, zp = rem - row * 75;
                        astore64(dst + e, *(const u64*)&smem[f * BUF_ + (HW_ + row) * ZW_ + 4 + 2 * zp]);
                    }
                }
            } else {
                if (h < NCH_ - 1) {
                    u64* dst = halo + (size_t)(((s * NBND_ + h) * 2 + 0) * 2 + par) * HELE_;
                    for (int e = tid - 256; e < HELE_; e += 256) {
                        const int f = e / 2400, rem = e - f * 2400, row = rem / 75, zp = rem - row * 75;
                        astore64(dst + e, *(const u64*)&smem[f * BUF_ + (w + row) * ZW_ + 4 + 2 * zp]);
                    }
                }
            }
            asm volatile("s_waitcnt vmcnt(0)" ::: "memory");   // drain own publishes
            __syncthreads();
            if (tid == 0) {
                if (h > 0)
                    astore32(&flags[(s * NBND_ + h - 1) * 2 + 1], r + 1);
                if (h < NCH_ - 1)
                    astore32(&flags[(s * NBND_ + h) * 2 + 0], r + 1);
            }
            // ---- distributed poll, then BATCHED ingest (1 wait, not 19) ----
            if (tid < 256) {
                if (h > 0) {
                    const int* fp = &flags[(s * NBND_ + h - 1) * 2 + 0];
                    while (aload32(fp) <= r) __builtin_amdgcn_s_sleep(1);
                    const u64* src = halo + (size_t)(((s * NBND_ + h - 1) * 2 + 0) * 2 + par) * HELE_;
                    u64 vb[NBATCH];
#pragma unroll
                    for (int q = 0; q < NBATCH; ++q) {
                        const int e = tid + 256 * q;
                        ld2_issue(vb[q], src + (e < HELE_ ? e : HELE_ - 1));
                    }
                    asm volatile("s_waitcnt vmcnt(0)" ::: "memory");
                    __builtin_amdgcn_sched_barrier(0);
#pragma unroll
                    for (int q = 0; q < NBATCH; ++q) {
                        const int e = tid + 256 * q;
                        if (e < HELE_) {
                            const int f = e / 2400, rem = e - f * 2400, row = rem / 75, zp = rem - row * 75;
                            *(u64*)&smem[f * BUF_ + row * ZW_ + 4 + 2 * zp] = vb[q];
                        }
                    }
                }
            } else {
                if (h < NCH_ - 1) {
                    const int* fp = &flags[(s * NBND_ + h) * 2 + 1];
                    while (aload32(fp) <= r) __builtin_amdgcn_s_sleep(1);
                    const u64* src = halo + (size_t)(((s * NBND_ + h) * 2 + 1) * 2 + par) * HELE_;
                    u64 vb[NBATCH];
#pragma unroll
                    for (int q = 0; q < NBATCH; ++q) {
                        const int e = (tid - 256) + 256 * q;
                        ld2_issue(vb[q], src + (e < HELE_ ? e : HELE_ - 1));
                    }
                    asm volatile("s_waitcnt vmcnt(0)" ::: "memory");
                    __builtin_amdgcn_sched_barrier(0);
#pragma unroll
                    for (int q = 0; q < NBATCH; ++q) {
                        const int e = (tid - 256) + 256 * q;
                        if (e < HELE_) {
                            const int f = e / 2400, rem = e - f * 2400, row = rem / 75, zp = rem - row * 75;
                            *(u64*)&smem[f * BUF_ + (rhi + row) * ZW_ + 4 + 2 * zp] = vb[q];
                        }
                    }
                }
            }
            __syncthreads();
            // ---- refresh register-prev for halo rows from ingested u(t+7) (buf1) ----
            if (comp) {
#pragma unroll
                for (int i = 0; i < 8; ++i) {
                    const int row = rbase + i;
                    if (row < HW_ || row >= rhi) {
                        pv_r[i] = *(const f4*)&smem[BUF_ + row * ZW_ + c0];
                    }
                }
            }
            __syncthreads();
        }
    }
}

extern "C" void kernel_launch(void* const* d_in, const int* in_sizes, int n_in,
                              void* d_out, int out_size, void* d_ws, size_t ws_size,
                              hipStream_t stream) {
    const float* v_map = (const float*)d_in[0];
    const float* s_amp = (const float*)d_in[1];
    const int*   s_loc = (const int*)d_in[2];
    const int*   r_loc = (const int*)d_in[3];
    float* out = (float*)d_out;

    int* flags = (int*)d_ws;                        // 64 ints
    u64* halo  = (u64*)((char*)d_ws + 1024);        // 4*8*2*2*4800*8 = 4.92 MB

    hipMemsetAsync(d_ws, 0, 1024, stream);          // reset flags each call

    const int smem_bytes = 2 * BUF_ * 4;            // 131,712 B
    static bool attr_set = false;
    if (!attr_set) {                                // host-side, idempotent
        hipFuncSetAttribute((const void*)wave_rp2,
                            hipFuncAttributeMaxDynamicSharedMemorySize, smem_bytes);
        attr_set = true;
    }

    wave_rp2<<<dim3(NS_ * NCH_), dim3(THR_), smem_bytes, stream>>>(
        v_map, s_amp, s_loc, r_loc, out, flags, halo);
}

// Round 9
// 2912.652 us; speedup vs baseline: 1.5746x; 1.0577x over previous
//
#include <hip/hip_runtime.h>

// 2D acoustic FD, 4 shots x 1000 steps. Temporal blocking K=8, 9 x-chunks/shot,
// full z in LDS (transposed). Protocol = R6 (agent-scope publish, flags,
// batched sc0sc1 ingest). R9: latency hiding only —
//  (a) u(t+7) halo strip published right after step k=7 (flies during step 8)
//  (b) next round's k=1 split: interior-safe rows computed BEFORE poll/ingest,
//      halo-dependent edge rows after. Compute inner loop byte-equal to R6.

#define NZ_ 150
#define NX_ 300
#define NT_ 1000
#define NS_ 4
#define NR_ 400
#define KS_ 8
#define NCH_ 9
#define NBND_ 8
#define HW_ 32               // halo width = 4*KS
#define ZW_ 168              // LDS z-stride
#define LROWS_ 98            // 32 + 34 + 32
#define BUF_ (LROWS_*ZW_)
#define THR_ 512
#define NRND_ 125
#define HELE_ 4800           // u64 per (s,bnd,dir,par): 2 fields*32 rows*75 zpairs
#define NBATCH 19            // ceil(4800/256)

typedef float f4 __attribute__((ext_vector_type(4)));
typedef unsigned long long u64;

__device__ __forceinline__ void astore64(u64* p, u64 v) {
    __hip_atomic_store(p, v, __ATOMIC_RELAXED, __HIP_MEMORY_SCOPE_AGENT);
}
__device__ __forceinline__ int aload32(const int* p) {
    return __hip_atomic_load(p, __ATOMIC_RELAXED, __HIP_MEMORY_SCOPE_AGENT);
}
__device__ __forceinline__ void astore32(int* p, int v) {
    __hip_atomic_store(p, v, __ATOMIC_RELAXED, __HIP_MEMORY_SCOPE_AGENT);
}
__device__ __forceinline__ void ld2_issue(u64& d, const u64* p) {
    asm volatile("global_load_dwordx2 %0, %1, off sc0 sc1" : "=v"(d) : "v"(p));
}

// One FD step over rows in [lo1,hi1) U [lo2,hi2)  (R6 inner body, 2-interval guard)
__device__ __forceinline__ void fd_step(
    float* __restrict__ smem, const int cb, const int nb,
    const int lo1, const int hi1, const int lo2, const int hi2,
    const bool comp, const int rbase, const int c0, const int zg, const f4* v2r,
    const int srow, const int szg, const int scol, const float srcadd)
{
    if (!comp) return;
    if (!((rbase < hi1 && rbase + 8 > lo1) || (rbase < hi2 && rbase + 8 > lo2))) return;
    const float* cur = smem + cb;
    float*       nxt = smem + nb;
    f4 W[9];
#pragma unroll
    for (int q = 0; q < 8; ++q) {
        int rr = rbase - 4 + q; rr = rr < 0 ? 0 : rr;
        W[q] = *(const f4*)&cur[rr * ZW_ + c0];
    }
#pragma unroll
    for (int i = 0; i < 8; ++i) {
        const int row = rbase + i;
        const int wr = (row + 4 < LROWS_) ? (row + 4) : (LROWS_ - 1);
        W[8] = *(const f4*)&cur[wr * ZW_ + c0];
        const bool act = (row >= lo1 && row < hi1) || (row >= lo2 && row < hi2);
        if (act) {
            const f4 lf = *(const f4*)&cur[row * ZW_ + c0 - 4];
            const f4 rt = *(const f4*)&cur[row * ZW_ + c0 + 4];
            const f4 pv = *(const f4*)&nxt[row * ZW_ + c0];
            float xw[12];
#pragma unroll
            for (int j = 0; j < 4; ++j) { xw[j] = lf[j]; xw[4 + j] = W[4][j]; xw[8 + j] = rt[j]; }
            f4 res;
#pragma unroll
            for (int j = 0; j < 4; ++j) {
                const float ct = xw[4 + j];
                float lap = 2.0f * (-205.0f / 72.0f) * ct;
                lap += (8.0f / 5.0f)    * ((xw[j + 3] + xw[j + 5]) + (W[3][j] + W[5][j]));
                lap += (-1.0f / 5.0f)   * ((xw[j + 2] + xw[j + 6]) + (W[2][j] + W[6][j]));
                lap += (8.0f / 315.0f)  * ((xw[j + 1] + xw[j + 7]) + (W[1][j] + W[7][j]));
                lap += (-1.0f / 560.0f) * ((xw[j + 0] + xw[j + 8]) + (W[0][j] + W[8][j]));
                res[j] = 2.0f * ct - pv[j] + v2r[i][j] * lap;
            }
            if (zg != 37) {
                *(f4*)&nxt[row * ZW_ + c0] = res;
            } else {                               // z=148,149; keep pads zero
                nxt[row * ZW_ + c0]     = res[0];
                nxt[row * ZW_ + c0 + 1] = res[1];
            }
            if (row == srow && zg == szg)
                nxt[row * ZW_ + scol] += srcadd;
        }
#pragma unroll
        for (int q = 0; q < 8; ++q) W[q] = W[q + 1];
    }
}

__global__ __launch_bounds__(THR_) void wave_ov(
    const float* __restrict__ v_map, const float* __restrict__ s_amp,
    const int* __restrict__ s_loc, const int* __restrict__ r_loc,
    float* __restrict__ out, int* __restrict__ flags, u64* __restrict__ halo)
{
    extern __shared__ float smem[];
    const int bi = blockIdx.x;
    const int s = bi & 3;
    const int h = bi >> 2;                       // 0..8
    const int tid = threadIdx.x;

    const int w  = 33 + (h < 3 ? 1 : 0);
    const int x0 = 33 * h + (h < 3 ? h : 3);
    const int rhi = HW_ + w;

    for (int i = tid; i < 2 * BUF_; i += THR_) smem[i] = 0.0f;

    const int zg = tid % 38;                     // 4-wide z group (R6 layout)
    const int xp = tid / 38;                     // x-slice, 8 rows each
    const bool comp = (tid < 494);               // 38*13
    const int c0 = 4 + 4 * zg;
    const int rbase = 8 * xp;

    f4 v2r[8];
#pragma unroll
    for (int i = 0; i < 8; ++i) {
        f4 vv = {0.f, 0.f, 0.f, 0.f};
        const int row = rbase + i;
        const int x = x0 - HW_ + row;
        if (comp && x >= 0 && x < NX_) {
#pragma unroll
            for (int j = 0; j < 4; ++j) {
                const int z = min(4 * zg + j, NZ_ - 1);
                const float v = v_map[z * NX_ + x] * 0.001f;
                vv[j] = v * v * 0.01f;           // (v*DT)^2 / DX^2
            }
        }
        v2r[i] = vv;
    }

    const int sz = s_loc[2 * s], sx = s_loc[2 * s + 1];
    float sS = v_map[sz * NX_ + sx] * 0.001f; sS = sS * sS;   // (v*DT)^2
    const int srow = sx - x0 + HW_;
    const int szg = sz >> 2;
    const int scol = 4 + sz;

    bool rown = false; int rrow = 0, rcol = 0;
    if (tid < NR_) {
        const int rz = r_loc[2 * tid];
        const int rx = r_loc[2 * tid + 1];
        if (rx >= x0 && rx < x0 + w) { rown = true; rrow = HW_ + rx - x0; rcol = 4 + rz; }
    }

    const int L1 = (h == 0)        ? HW_ : HW_ - 28;   // k=1 region bounds
    const int R1 = (h == NCH_ - 1) ? rhi : rhi + 28;

    __syncthreads();

    for (int r = 0; r < NRND_; ++r) {
        const int kstart = (r == 0) ? 1 : 2;           // k=1 of rounds >=1 done in transition
        for (int k = kstart; k <= KS_; ++k) {
            const int tau = KS_ * r + k;
            const int ext = 4 * (KS_ - k);
            const int L  = (h == 0)        ? HW_ : HW_ - ext;
            const int R  = (h == NCH_ - 1) ? rhi : rhi + ext;
            fd_step(smem, ((tau + 1) & 1) * BUF_, (tau & 1) * BUF_,
                    L, R, 0, 0, comp, rbase, c0, zg, v2r,
                    srow, szg, scol, sS * s_amp[s * NT_ + tau - 1]);
            __syncthreads();
            // (a) early publish of u(t+7)=buf1 halo strip; flies during step 8
            if (k == 7 && r < NRND_ - 1) {
                const int par = r & 1;
                if (tid < 256) {
                    if (h > 0) {
                        u64* dst = halo + (size_t)(((s * NBND_ + h - 1) * 2 + 1) * 2 + par) * HELE_;
                        for (int e = tid; e < 2400; e += 256) {
                            const int row = e / 75, zp = e - row * 75;
                            astore64(dst + 2400 + e, *(const u64*)&smem[BUF_ + (HW_ + row) * ZW_ + 4 + 2 * zp]);
                        }
                    }
                } else {
                    if (h < NCH_ - 1) {
                        u64* dst = halo + (size_t)(((s * NBND_ + h) * 2 + 0) * 2 + par) * HELE_;
                        for (int e = tid - 256; e < 2400; e += 256) {
                            const int row = e / 75, zp = e - row * 75;
                            astore64(dst + 2400 + e, *(const u64*)&smem[BUF_ + (w + row) * ZW_ + 4 + 2 * zp]);
                        }
                    }
                }
            }
            if (rown) {
                const float* nb = smem + (tau & 1) * BUF_;
                out[((size_t)s * NT_ + (tau - 1)) * NR_ + tid] = nb[rrow * ZW_ + rcol];
            }
        }

        if (r < NRND_ - 1) {
            const int par = r & 1;
            const int tau1 = KS_ * (r + 1) + 1;        // next round's step 1 (odd -> nxt=buf1)
            // ---- publish u(t+8)=buf0 strip (f=0 elements) ----
            if (tid < 256) {
                if (h > 0) {
                    u64* dst = halo + (size_t)(((s * NBND_ + h - 1) * 2 + 1) * 2 + par) * HELE_;
                    for (int e = tid; e < 2400; e += 256) {
                        const int row = e / 75, zp = e - row * 75;
                        astore64(dst + e, *(const u64*)&smem[(HW_ + row) * ZW_ + 4 + 2 * zp]);
                    }
                }
            } else {
                if (h < NCH_ - 1) {
                    u64* dst = halo + (size_t)(((s * NBND_ + h) * 2 + 0) * 2 + par) * HELE_;
                    for (int e = tid - 256; e < 2400; e += 256) {
                        const int row = e / 75, zp = e - row * 75;
                        astore64(dst + e, *(const u64*)&smem[(w + row) * ZW_ + 4 + 2 * zp]);
                    }
                }
            }
            asm volatile("s_waitcnt vmcnt(0)" ::: "memory");   // drain f0 + early f1
            __syncthreads();
            if (tid == 0) {
                if (h > 0)      astore32(&flags[(s * NBND_ + h - 1) * 2 + 1], r + 1);
                if (h < NCH_ - 1) astore32(&flags[(s * NBND_ + h) * 2 + 0], r + 1);
            }
            // ---- (b) interior-safe part of k=1 while neighbor flag is in flight ----
            fd_step(smem, 0 /*buf0 = u(t+8)*/, BUF_ /*buf1: pv=u(t+7) -> u(t+9)*/,
                    HW_ + 4, rhi - 4, 0, 0, comp, rbase, c0, zg, v2r,
                    srow, szg, scol, sS * s_amp[s * NT_ + tau1 - 1]);
            // (no barrier: ingest below writes only halo rows, disjoint from the
            //  interior rows written above; per-thread order is program order)
            // ---- distributed poll + batched ingest (halo rows of both buffers) ----
            if (tid < 256) {
                if (h > 0) {
                    const int* fp = &flags[(s * NBND_ + h - 1) * 2 + 0];
                    while (aload32(fp) <= r) __builtin_amdgcn_s_sleep(1);
                    const u64* src = halo + (size_t)(((s * NBND_ + h - 1) * 2 + 0) * 2 + par) * HELE_;
                    u64 vb[NBATCH];
#pragma unroll
                    for (int q = 0; q < NBATCH; ++q) {
                        const int e = tid + 256 * q;
                        ld2_issue(vb[q], src + (e < HELE_ ? e : HELE_ - 1));
                    }
                    asm volatile("s_waitcnt vmcnt(0)" ::: "memory");
                    __builtin_amdgcn_sched_barrier(0);
#pragma unroll
                    for (int q = 0; q < NBATCH; ++q) {
                        const int e = tid + 256 * q;
                        if (e < HELE_) {
                            const int f = e / 2400, rem = e - f * 2400, row = rem / 75, zp = rem - row * 75;
                            *(u64*)&smem[f * BUF_ + row * ZW_ + 4 + 2 * zp] = vb[q];
                        }
                    }
                }
            } else {
                if (h < NCH_ - 1) {
                    const int* fp = &flags[(s * NBND_ + h) * 2 + 1];
                    while (aload32(fp) <= r) __builtin_amdgcn_s_sleep(1);
                    const u64* src = halo + (size_t)(((s * NBND_ + h) * 2 + 1) * 2 + par) * HELE_;
                    u64 vb[NBATCH];
#pragma unroll
                    for (int q = 0; q < NBATCH; ++q) {
                        const int e = (tid - 256) + 256 * q;
                        ld2_issue(vb[q], src + (e < HELE_ ? e : HELE_ - 1));
                    }
                    asm volatile("s_waitcnt vmcnt(0)" ::: "memory");
                    __builtin_amdgcn_sched_barrier(0);
#pragma unroll
                    for (int q = 0; q < NBATCH; ++q) {
                        const int e = (tid - 256) + 256 * q;
                        if (e < HELE_) {
                            const int f = e / 2400, rem = e - f * 2400, row = rem / 75, zp = rem - row * 75;
                            *(u64*)&smem[f * BUF_ + (rhi + row) * ZW_ + 4 + 2 * zp] = vb[q];
                        }
                    }
                }
            }
            __syncthreads();
            // ---- edge part of k=1 (needs fresh halos) ----
            fd_step(smem, 0, BUF_, L1, HW_ + 4, rhi - 4, R1,
                    comp, rbase, c0, zg, v2r,
                    srow, szg, scol, sS * s_amp[s * NT_ + tau1 - 1]);
            __syncthreads();
            if (rown)
                out[((size_t)s * NT_ + (tau1 - 1)) * NR_ + tid] = smem[BUF_ + rrow * ZW_ + rcol];
        }
    }
}

extern "C" void kernel_launch(void* const* d_in, const int* in_sizes, int n_in,
                              void* d_out, int out_size, void* d_ws, size_t ws_size,
                              hipStream_t stream) {
    const float* v_map = (const float*)d_in[0];
    const float* s_amp = (const float*)d_in[1];
    const int*   s_loc = (const int*)d_in[2];
    const int*   r_loc = (const int*)d_in[3];
    float* out = (float*)d_out;

    int* flags = (int*)d_ws;                        // 64 ints
    u64* halo  = (u64*)((char*)d_ws + 1024);        // 4*8*2*2*4800*8 = 4.92 MB

    hipMemsetAsync(d_ws, 0, 1024, stream);          // reset flags each call

    const int smem_bytes = 2 * BUF_ * 4;            // 131,712 B
    static bool attr_set = false;
    if (!attr_set) {                                // host-side, idempotent
        hipFuncSetAttribute((const void*)wave_ov,
                            hipFuncAttributeMaxDynamicSharedMemorySize, smem_bytes);
        attr_set = true;
    }

    wave_ov<<<dim3(NS_ * NCH_), dim3(THR_), smem_bytes, stream>>>(
        v_map, s_amp, s_loc, r_loc, out, flags, halo);
}